// Round 2
// baseline (3480.372 us; speedup 1.0000x reference)
//
#include <hip/hip_runtime.h>
#include <math.h>

#define N_NODES 100000
#define N_EDGES 1600000
#define IN_F 64
#define OUT_F 64
#define KK 4
#define KOUT (KK * OUT_F)   // 256
#define EPS 1e-15f

// ---- module-global scratch (avoids any dependence on ws_size) ----
__device__ float g_deg[N_NODES];
__device__ float g_isd[N_NODES];
__device__ float g_h[(size_t)N_NODES * KOUT];     // 98.4 MB
__device__ float g_agg[(size_t)N_NODES * OUT_F];  // 25.6 MB

// ---------------- kernel 0: zero deg + agg ----------------
__global__ void zero_kernel() {
    int i = blockIdx.x * blockDim.x + threadIdx.x;
    if (i < N_NODES) g_deg[i] = 0.0f;
    // zero agg: N_NODES*64 elements, grid covers it
    for (size_t j = i; j < (size_t)N_NODES * OUT_F; j += (size_t)gridDim.x * blockDim.x)
        g_agg[j] = 0.0f;
}

// ---------------- kernel 1: in-degree histogram ----------------
__global__ void deg_kernel(const int* __restrict__ dst) {
    int e = blockIdx.x * blockDim.x + threadIdx.x;
    if (e < N_EDGES) atomicAdd(&g_deg[dst[e]], 1.0f);
}

// ---------------- kernel 2: inv sqrt degree ----------------
__global__ void isd_kernel() {
    int n = blockIdx.x * blockDim.x + threadIdx.x;
    if (n < N_NODES) {
        float d = g_deg[n];
        g_isd[n] = (d > 0.0f) ? rsqrtf(d) : 0.0f;
    }
}

// ---------------- kernel 3: h = x @ g  ([N,64]x[64,256] -> [N,256]) ----------------
// 16 nodes per block of 256; thread t owns output column t
#define H_NPB 16
__global__ void h_kernel(const float* __restrict__ x, const float* __restrict__ g) {
    __shared__ float xs[H_NPB][IN_F];
    int t = threadIdx.x;             // 0..255 = output column
    int n0 = blockIdx.x * H_NPB;
    // load x tile: 16*64 = 1024 floats, 4 per thread
#pragma unroll
    for (int r = 0; r < 4; ++r) {
        int idx = r * 256 + t;       // 0..1023
        int nn = idx >> 6, ii = idx & 63;
        int n = n0 + nn;
        xs[nn][ii] = (n < N_NODES) ? x[n * IN_F + ii] : 0.0f;
    }
    __syncthreads();
    float acc[H_NPB];
#pragma unroll
    for (int n = 0; n < H_NPB; ++n) acc[n] = 0.0f;
#pragma unroll
    for (int i = 0; i < IN_F; ++i) {
        float gv = g[i * KOUT + t];
#pragma unroll
        for (int n = 0; n < H_NPB; ++n) acc[n] += xs[n][i] * gv;
    }
#pragma unroll
    for (int n = 0; n < H_NPB; ++n) {
        int node = n0 + n;
        if (node < N_NODES) g_h[(size_t)node * KOUT + t] = acc[n];
    }
}

// ---------------- kernel 4: edge gather + mixture + atomic scatter ----------------
// one wave (64 lanes) per edge; lane = output channel
__global__ void edge_kernel(const int* __restrict__ src, const int* __restrict__ dst,
                            const float* __restrict__ mu, const float* __restrict__ sigma) {
    int e = blockIdx.x * 4 + (threadIdx.x >> 6);
    if (e >= N_EDGES) return;
    int lane = threadIdx.x & 63;
    int s = src[e];
    int d = dst[e];
    float a0 = g_isd[s];
    float a1 = g_isd[d];
    float m = 0.0f;
    const float* hp = &g_h[(size_t)s * KOUT + lane];
#pragma unroll
    for (int k = 0; k < KK; ++k) {
        float mu0 = mu[k * 2 + 0], mu1 = mu[k * 2 + 1];
        float s0 = sigma[k * 2 + 0], s1 = sigma[k * 2 + 1];
        float d0 = a0 - mu0, d1 = a1 - mu1;
        float ex = -0.5f * (d0 * d0 / (EPS + s0 * s0) + d1 * d1 / (EPS + s1 * s1));
        float gk = __expf(ex);
        m += gk * hp[k * OUT_F];
    }
    atomicAdd(&g_agg[(size_t)d * OUT_F + lane], m);
}

// ---------------- kernel 5: out = agg/max(deg,1) + x@root_w + bias ----------------
// 16 nodes per block of 256; thread t: column o=t&63, handles 4 nodes
__global__ void final_kernel(const float* __restrict__ x, const float* __restrict__ rw,
                             const float* __restrict__ bias, float* __restrict__ out) {
    __shared__ float xs[16][IN_F];
    int t = threadIdx.x;
    int n0 = blockIdx.x * 16;
    int o = t & 63;
    int grp = t >> 6;                // 0..3; handles nodes grp*4 .. grp*4+3
#pragma unroll
    for (int r = 0; r < 4; ++r) {
        int idx = r * 256 + t;
        int nn = idx >> 6, ii = idx & 63;
        int n = n0 + nn;
        xs[nn][ii] = (n < N_NODES) ? x[n * IN_F + ii] : 0.0f;
    }
    __syncthreads();
    float acc[4];
#pragma unroll
    for (int q = 0; q < 4; ++q) acc[q] = 0.0f;
#pragma unroll
    for (int i = 0; i < IN_F; ++i) {
        float rv = rw[i * OUT_F + o];
#pragma unroll
        for (int q = 0; q < 4; ++q) acc[q] += xs[grp * 4 + q][i] * rv;
    }
    float b = bias[o];
#pragma unroll
    for (int q = 0; q < 4; ++q) {
        int n = n0 + grp * 4 + q;
        if (n < N_NODES) {
            float dg = g_deg[n];
            float dv = (dg > 1.0f) ? dg : 1.0f;
            out[(size_t)n * OUT_F + o] = g_agg[(size_t)n * OUT_F + o] / dv + acc[q] + b;
        }
    }
}

extern "C" void kernel_launch(void* const* d_in, const int* in_sizes, int n_in,
                              void* d_out, int out_size, void* d_ws, size_t ws_size,
                              hipStream_t stream) {
    const float* x     = (const float*)d_in[0];
    const int*   ei    = (const int*)d_in[1];     // int64 in reference -> int32 from harness
    const float* g     = (const float*)d_in[2];
    const float* mu    = (const float*)d_in[3];
    const float* sigma = (const float*)d_in[4];
    const float* rw    = (const float*)d_in[5];
    const float* bias  = (const float*)d_in[6];
    float* out = (float*)d_out;

    const int* src = ei;            // [2,E] row-major
    const int* dst = ei + N_EDGES;

    zero_kernel<<<4096, 256, 0, stream>>>();
    deg_kernel<<<(N_EDGES + 255) / 256, 256, 0, stream>>>(dst);
    isd_kernel<<<(N_NODES + 255) / 256, 256, 0, stream>>>();
    h_kernel<<<(N_NODES + H_NPB - 1) / H_NPB, 256, 0, stream>>>(x, g);
    edge_kernel<<<(N_EDGES + 3) / 4, 256, 0, stream>>>(src, dst, mu, sigma);
    final_kernel<<<(N_NODES + 15) / 16, 256, 0, stream>>>(x, rw, bias, out);
}

// Round 3
// 736.123 us; speedup vs baseline: 4.7280x; 4.7280x over previous
//
#include <hip/hip_runtime.h>
#include <math.h>

#define N_NODES 100000
#define N_EDGES 1600000
#define IN_F 64
#define OUT_F 64
#define KK 4
#define KOUT (KK * OUT_F)   // 256
#define EPS 1e-15f

// ---- module-global scratch (no dependence on ws_size) ----
__device__ float g_deg[N_NODES];
__device__ float g_isd[N_NODES];
__device__ float g_h[(size_t)N_NODES * KOUT];     // 98.4 MB
__device__ float g_agg[(size_t)N_NODES * OUT_F];  // 25.6 MB

// ---------------- kernel 0: zero deg + agg ----------------
__global__ void zero_kernel() {
    int i = blockIdx.x * blockDim.x + threadIdx.x;
    if (i < N_NODES) g_deg[i] = 0.0f;
    for (size_t j = i; j < (size_t)N_NODES * OUT_F; j += (size_t)gridDim.x * blockDim.x)
        g_agg[j] = 0.0f;
}

// ---------------- kernel 1: in-degree histogram ----------------
__global__ void deg_kernel(const int* __restrict__ dst) {
    int e = blockIdx.x * blockDim.x + threadIdx.x;
    if (e < N_EDGES) atomicAdd(&g_deg[dst[e]], 1.0f);
}

// ---------------- kernel 2: inv sqrt degree ----------------
__global__ void isd_kernel() {
    int n = blockIdx.x * blockDim.x + threadIdx.x;
    if (n < N_NODES) {
        float d = g_deg[n];
        g_isd[n] = (d > 0.0f) ? rsqrtf(d) : 0.0f;
    }
}

// ---------------- kernel 3: h = x @ g  ([N,64]x[64,256] -> [N,256]) ----------------
// 8 nodes per block of 256; thread t owns output column t for all 8 nodes.
// acc[8] + bounded unroll keeps VGPR demand low (the R1 version spilled:
// 16 accs + 64-deep load pipeline at VGPR_Count=64 -> 6 GB of scratch writes).
#define H_NPB 8
__global__ __launch_bounds__(256, 2) void h_kernel(const float* __restrict__ x,
                                                   const float* __restrict__ g) {
    __shared__ float xs[H_NPB][IN_F];
    int t = threadIdx.x;             // 0..255 = output column
    int n0 = blockIdx.x * H_NPB;
#pragma unroll
    for (int r = 0; r < 2; ++r) {
        int idx = r * 256 + t;       // 0..511
        int nn = idx >> 6, ii = idx & 63;
        int n = n0 + nn;
        xs[nn][ii] = (n < N_NODES) ? x[n * IN_F + ii] : 0.0f;
    }
    __syncthreads();
    float acc[H_NPB];
#pragma unroll
    for (int n = 0; n < H_NPB; ++n) acc[n] = 0.0f;
#pragma unroll 8
    for (int i = 0; i < IN_F; ++i) {
        float gv = g[i * KOUT + t];
#pragma unroll
        for (int n = 0; n < H_NPB; ++n) acc[n] += xs[n][i] * gv;
    }
#pragma unroll
    for (int n = 0; n < H_NPB; ++n) {
        int node = n0 + n;
        if (node < N_NODES) g_h[(size_t)node * KOUT + t] = acc[n];
    }
}

// ---------------- kernel 4: edge gather + mixture + atomic scatter ----------------
// one wave (64 lanes) per edge; lane = output channel
__global__ void edge_kernel(const int* __restrict__ src, const int* __restrict__ dst,
                            const float* __restrict__ mu, const float* __restrict__ sigma) {
    int e = blockIdx.x * 4 + (threadIdx.x >> 6);
    if (e >= N_EDGES) return;
    int lane = threadIdx.x & 63;
    int s = src[e];
    int d = dst[e];
    float a0 = g_isd[s];
    float a1 = g_isd[d];
    float m = 0.0f;
    const float* hp = &g_h[(size_t)s * KOUT + lane];
#pragma unroll
    for (int k = 0; k < KK; ++k) {
        float mu0 = mu[k * 2 + 0], mu1 = mu[k * 2 + 1];
        float s0 = sigma[k * 2 + 0], s1 = sigma[k * 2 + 1];
        float d0 = a0 - mu0, d1 = a1 - mu1;
        float ex = -0.5f * (d0 * d0 / (EPS + s0 * s0) + d1 * d1 / (EPS + s1 * s1));
        float gk = __expf(ex);
        m += gk * hp[k * OUT_F];
    }
    atomicAdd(&g_agg[(size_t)d * OUT_F + lane], m);
}

// ---------------- kernel 5: out = agg/max(deg,1) + x@root_w + bias ----------------
// 8 nodes per block of 256; thread t: column o=t&63, handles 2 nodes
__global__ __launch_bounds__(256, 2) void final_kernel(const float* __restrict__ x,
                                                       const float* __restrict__ rw,
                                                       const float* __restrict__ bias,
                                                       float* __restrict__ out) {
    __shared__ float xs[8][IN_F];
    int t = threadIdx.x;
    int n0 = blockIdx.x * 8;
    int o = t & 63;
    int grp = t >> 6;                // 0..3; handles nodes grp*2, grp*2+1
#pragma unroll
    for (int r = 0; r < 2; ++r) {
        int idx = r * 256 + t;
        int nn = idx >> 6, ii = idx & 63;
        int n = n0 + nn;
        xs[nn][ii] = (n < N_NODES) ? x[n * IN_F + ii] : 0.0f;
    }
    __syncthreads();
    float acc[2] = {0.0f, 0.0f};
#pragma unroll 8
    for (int i = 0; i < IN_F; ++i) {
        float rv = rw[i * OUT_F + o];
#pragma unroll
        for (int q = 0; q < 2; ++q) acc[q] += xs[grp * 2 + q][i] * rv;
    }
    float b = bias[o];
#pragma unroll
    for (int q = 0; q < 2; ++q) {
        int n = n0 + grp * 2 + q;
        if (n < N_NODES) {
            float dg = g_deg[n];
            float dv = (dg > 1.0f) ? dg : 1.0f;
            out[(size_t)n * OUT_F + o] = g_agg[(size_t)n * OUT_F + o] / dv + acc[q] + b;
        }
    }
}

extern "C" void kernel_launch(void* const* d_in, const int* in_sizes, int n_in,
                              void* d_out, int out_size, void* d_ws, size_t ws_size,
                              hipStream_t stream) {
    const float* x     = (const float*)d_in[0];
    const int*   ei    = (const int*)d_in[1];     // int64 in reference -> int32 from harness
    const float* g     = (const float*)d_in[2];
    const float* mu    = (const float*)d_in[3];
    const float* sigma = (const float*)d_in[4];
    const float* rw    = (const float*)d_in[5];
    const float* bias  = (const float*)d_in[6];
    float* out = (float*)d_out;

    const int* src = ei;            // [2,E] row-major
    const int* dst = ei + N_EDGES;

    zero_kernel<<<4096, 256, 0, stream>>>();
    deg_kernel<<<(N_EDGES + 255) / 256, 256, 0, stream>>>(dst);
    isd_kernel<<<(N_NODES + 255) / 256, 256, 0, stream>>>();
    h_kernel<<<(N_NODES + H_NPB - 1) / H_NPB, 256, 0, stream>>>(x, g);
    edge_kernel<<<(N_EDGES + 3) / 4, 256, 0, stream>>>(src, dst, mu, sigma);
    final_kernel<<<(N_NODES + 7) / 8, 256, 0, stream>>>(x, rw, bias, out);
}

// Round 5
// 717.731 us; speedup vs baseline: 4.8491x; 1.0256x over previous
//
#include <hip/hip_runtime.h>
#include <math.h>

#define N_NODES 100000
#define N_EDGES 1600000
#define IN_F 64
#define OUT_F 64
#define KK 4
#define KOUT (KK * OUT_F)   // 256
#define EPS 1e-15f

// ---- module-global scratch (no dependence on ws_size) ----
__device__ float  g_deg[N_NODES];
__device__ float  g_isd[N_NODES];
__device__ uint2  g_hp[(size_t)N_NODES * OUT_F];   // h packed: [node][ch] -> 4x bf16 (k=0..3), 51.2 MB
__device__ float  g_agg[(size_t)N_NODES * OUT_F];  // 25.6 MB
__device__ float4 g_gauss[N_EDGES];                // per-edge mixture weights, 25.6 MB
__device__ float  g_w2[KK * 2];                    // -0.5/(eps+sigma^2)

static __device__ __forceinline__ unsigned short f2bf(float f) {
    unsigned int u = __float_as_uint(f);
    unsigned int r = u + 0x7fffu + ((u >> 16) & 1u);   // RNE
    return (unsigned short)(r >> 16);
}
static __device__ __forceinline__ float bflo(unsigned int u) { return __uint_as_float(u << 16); }
static __device__ __forceinline__ float bfhi(unsigned int u) { return __uint_as_float(u & 0xffff0000u); }

// ---------------- kernel 0: zero deg + agg ----------------
__global__ void zero_kernel() {
    int i = blockIdx.x * blockDim.x + threadIdx.x;
    if (i < N_NODES) g_deg[i] = 0.0f;
    for (size_t j = i; j < (size_t)N_NODES * OUT_F; j += (size_t)gridDim.x * blockDim.x)
        g_agg[j] = 0.0f;
}

// ---------------- kernel 1: in-degree histogram ----------------
__global__ void deg_kernel(const int* __restrict__ dst) {
    int e = blockIdx.x * blockDim.x + threadIdx.x;
    if (e < N_EDGES) atomicAdd(&g_deg[dst[e]], 1.0f);
}

// ---------------- kernel 2: isd + sigma reciprocals ----------------
__global__ void isd_kernel(const float* __restrict__ sigma) {
    int n = blockIdx.x * blockDim.x + threadIdx.x;
    if (n < KK * 2) {
        float s = sigma[n];
        g_w2[n] = -0.5f / (EPS + s * s);
    }
    if (n < N_NODES) {
        float d = g_deg[n];
        g_isd[n] = (d > 0.0f) ? rsqrtf(d) : 0.0f;
    }
}

// ---------------- kernel 3: h = x @ g, packed to bf16 [node][ch][k] ----------------
// 8 nodes per block of 256; thread t owns output column t=(k,ch) for all 8 nodes.
#define H_NPB 8
__global__ __launch_bounds__(256, 2) void h_kernel(const float* __restrict__ x,
                                                   const float* __restrict__ g) {
    __shared__ float xs[H_NPB][IN_F];
    __shared__ unsigned short hs[H_NPB][OUT_F][KK];  // 4 KB staging for pack
    int t = threadIdx.x;             // 0..255 = output column (k = t>>6, ch = t&63)
    int n0 = blockIdx.x * H_NPB;
#pragma unroll
    for (int r = 0; r < 2; ++r) {
        int idx = r * 256 + t;       // 0..511
        int nn = idx >> 6, ii = idx & 63;
        int n = n0 + nn;
        xs[nn][ii] = (n < N_NODES) ? x[n * IN_F + ii] : 0.0f;
    }
    __syncthreads();
    float acc[H_NPB];
#pragma unroll
    for (int n = 0; n < H_NPB; ++n) acc[n] = 0.0f;
#pragma unroll 8
    for (int i = 0; i < IN_F; ++i) {
        float gv = g[i * KOUT + t];
#pragma unroll
        for (int n = 0; n < H_NPB; ++n) acc[n] += xs[n][i] * gv;
    }
    int k = t >> 6, ch = t & 63;
#pragma unroll
    for (int n = 0; n < H_NPB; ++n) hs[n][ch][k] = f2bf(acc[n]);
    __syncthreads();
    // store 512 packed uint2 (8 nodes x 64 ch), 2 per thread, coalesced
#pragma unroll
    for (int r = 0; r < 2; ++r) {
        int idx = r * 256 + t;
        int nn = idx >> 6, cc = idx & 63;
        int node = n0 + nn;
        if (node < N_NODES) {
            const unsigned short* p = &hs[nn][cc][0];
            uint2 v;
            v.x = (unsigned int)p[0] | ((unsigned int)p[1] << 16);
            v.y = (unsigned int)p[2] | ((unsigned int)p[3] << 16);
            g_hp[(size_t)node * OUT_F + cc] = v;
        }
    }
}

// ---------------- kernel 4a: per-edge gaussian weights ----------------
// 1 thread per edge (64x less redundancy than computing in the edge wave)
__global__ __launch_bounds__(256, 8) void gauss_kernel(const int* __restrict__ src,
                                                       const int* __restrict__ dst,
                                                       const float* __restrict__ mu) {
    int e = blockIdx.x * blockDim.x + threadIdx.x;
    if (e >= N_EDGES) return;
    float a0 = g_isd[src[e]];
    float a1 = g_isd[dst[e]];
    float w[KK];
#pragma unroll
    for (int k = 0; k < KK; ++k) {
        float d0 = a0 - mu[k * 2 + 0];
        float d1 = a1 - mu[k * 2 + 1];
        float ex = g_w2[k * 2 + 0] * d0 * d0 + g_w2[k * 2 + 1] * d1 * d1;
        w[k] = __expf(ex);           // base-e exp (R4 bug: had a spurious log2e factor)
    }
    g_gauss[e] = make_float4(w[0], w[1], w[2], w[3]);
}

// ---------------- kernel 4b: edge gather + scatter ----------------
// one wave (64 lanes) per edge; lane = output channel; ONE 8B load/lane for all 4 k
__global__ __launch_bounds__(256, 8) void edge_kernel(const int* __restrict__ src,
                                                      const int* __restrict__ dst) {
    int e = blockIdx.x * 4 + (threadIdx.x >> 6);
    if (e >= N_EDGES) return;
    int lane = threadIdx.x & 63;
    int s = src[e];
    int d = dst[e];
    float4 gw = g_gauss[e];
    uint2 hv = g_hp[(size_t)s * OUT_F + lane];
    float m = bflo(hv.x) * gw.x + bfhi(hv.x) * gw.y + bflo(hv.y) * gw.z + bfhi(hv.y) * gw.w;
    atomicAdd(&g_agg[(size_t)d * OUT_F + lane], m);
}

// ---------------- kernel 5: out = agg/max(deg,1) + x@root_w + bias ----------------
__global__ __launch_bounds__(256, 2) void final_kernel(const float* __restrict__ x,
                                                       const float* __restrict__ rw,
                                                       const float* __restrict__ bias,
                                                       float* __restrict__ out) {
    __shared__ float xs[8][IN_F];
    int t = threadIdx.x;
    int n0 = blockIdx.x * 8;
    int o = t & 63;
    int grp = t >> 6;                // 0..3; handles nodes grp*2, grp*2+1
#pragma unroll
    for (int r = 0; r < 2; ++r) {
        int idx = r * 256 + t;
        int nn = idx >> 6, ii = idx & 63;
        int n = n0 + nn;
        xs[nn][ii] = (n < N_NODES) ? x[n * IN_F + ii] : 0.0f;
    }
    __syncthreads();
    float acc[2] = {0.0f, 0.0f};
#pragma unroll 8
    for (int i = 0; i < IN_F; ++i) {
        float rv = rw[i * OUT_F + o];
#pragma unroll
        for (int q = 0; q < 2; ++q) acc[q] += xs[grp * 2 + q][i] * rv;
    }
    float b = bias[o];
#pragma unroll
    for (int q = 0; q < 2; ++q) {
        int n = n0 + grp * 2 + q;
        if (n < N_NODES) {
            float dg = g_deg[n];
            float dv = (dg > 1.0f) ? dg : 1.0f;
            out[(size_t)n * OUT_F + o] = g_agg[(size_t)n * OUT_F + o] / dv + acc[q] + b;
        }
    }
}

extern "C" void kernel_launch(void* const* d_in, const int* in_sizes, int n_in,
                              void* d_out, int out_size, void* d_ws, size_t ws_size,
                              hipStream_t stream) {
    const float* x     = (const float*)d_in[0];
    const int*   ei    = (const int*)d_in[1];     // int64 in reference -> int32 from harness
    const float* g     = (const float*)d_in[2];
    const float* mu    = (const float*)d_in[3];
    const float* sigma = (const float*)d_in[4];
    const float* rw    = (const float*)d_in[5];
    const float* bias  = (const float*)d_in[6];
    float* out = (float*)d_out;

    const int* src = ei;            // [2,E] row-major
    const int* dst = ei + N_EDGES;

    zero_kernel<<<4096, 256, 0, stream>>>();
    deg_kernel<<<(N_EDGES + 255) / 256, 256, 0, stream>>>(dst);
    isd_kernel<<<(N_NODES + 255) / 256, 256, 0, stream>>>(sigma);
    h_kernel<<<(N_NODES + H_NPB - 1) / H_NPB, 256, 0, stream>>>(x, g);
    gauss_kernel<<<(N_EDGES + 255) / 256, 256, 0, stream>>>(src, dst, mu);
    edge_kernel<<<(N_EDGES + 3) / 4, 256, 0, stream>>>(src, dst);
    final_kernel<<<(N_NODES + 7) / 8, 256, 0, stream>>>(x, rw, bias, out);
}

// Round 6
// 498.217 us; speedup vs baseline: 6.9856x; 1.4406x over previous
//
#include <hip/hip_runtime.h>
#include <math.h>

#define N_NODES 100000
#define N_EDGES 1600000
#define IN_F 64
#define OUT_F 64
#define KK 4
#define KOUT (KK * OUT_F)   // 256
#define EPS 1e-15f
#define NB ((N_NODES + 255) / 256)   // 391 scan blocks

// ---- module-global scratch ----
__device__ int    g_cnt[N_NODES];
__device__ int    g_off[N_NODES + 1];
__device__ int    g_cur[N_NODES];
__device__ int    g_bsum[512];
__device__ float  g_isd[N_NODES];
__device__ float  g_w2[KK * 2];                    // -0.5/(eps+sigma^2)
__device__ uint2  g_hp[(size_t)N_NODES * OUT_F];   // h packed: [node][ch] -> 4x bf16, 51.2 MB
__device__ int    g_csrc[N_EDGES];                 // src per edge, dst-bucket order
__device__ float4 g_cgauss[N_EDGES];               // gauss weights, dst-bucket order, 25.6 MB

static __device__ __forceinline__ unsigned short f2bf(float f) {
    unsigned int u = __float_as_uint(f);
    unsigned int r = u + 0x7fffu + ((u >> 16) & 1u);   // RNE
    return (unsigned short)(r >> 16);
}
static __device__ __forceinline__ float bflo(unsigned int u) { return __uint_as_float(u << 16); }
static __device__ __forceinline__ float bfhi(unsigned int u) { return __uint_as_float(u & 0xffff0000u); }

// ---------------- zero counts ----------------
__global__ void zero_kernel() {
    int i = blockIdx.x * blockDim.x + threadIdx.x;
    if (i < N_NODES) g_cnt[i] = 0;
    if (i == 0) g_off[N_NODES] = N_EDGES;
}

// ---------------- in-degree histogram (int) ----------------
__global__ void deg_kernel(const int* __restrict__ dst) {
    int e = blockIdx.x * blockDim.x + threadIdx.x;
    if (e < N_EDGES) atomicAdd(&g_cnt[dst[e]], 1);
}

// ---------------- scan 1: per-block exclusive scan of g_cnt ----------------
__global__ void scan1_kernel() {
    __shared__ int sh[256];
    int t = threadIdx.x;
    int i = blockIdx.x * 256 + t;
    int c = (i < N_NODES) ? g_cnt[i] : 0;
    sh[t] = c;
    __syncthreads();
#pragma unroll
    for (int d = 1; d < 256; d <<= 1) {
        int v = (t >= d) ? sh[t - d] : 0;
        __syncthreads();
        sh[t] += v;
        __syncthreads();
    }
    int incl = sh[t];
    if (i < N_NODES) g_off[i] = incl - c;        // local exclusive
    if (t == 255) g_bsum[blockIdx.x] = incl;     // block total
}

// ---------------- scan 2: exclusive scan of 391 block sums (one block) ----------------
__global__ void scan2_kernel() {
    __shared__ int sh[512];
    int t = threadIdx.x;                         // 0..511
    int v = (t < NB) ? g_bsum[t] : 0;
    sh[t] = v;
    __syncthreads();
#pragma unroll
    for (int d = 1; d < 512; d <<= 1) {
        int u = (t >= d) ? sh[t - d] : 0;
        __syncthreads();
        sh[t] += u;
        __syncthreads();
    }
    if (t < NB) g_bsum[t] = sh[t] - v;           // exclusive
}

// ---------------- scan 3: add-back + cursors + isd + w2 ----------------
__global__ void scan3_kernel(const float* __restrict__ sigma) {
    int i = blockIdx.x * blockDim.x + threadIdx.x;
    if (i < KK * 2) {
        float s = sigma[i];
        g_w2[i] = -0.5f / (EPS + s * s);
    }
    if (i < N_NODES) {
        int off = g_off[i] + g_bsum[i >> 8];
        g_off[i] = off;
        g_cur[i] = off;
        int c = g_cnt[i];
        g_isd[i] = (c > 0) ? rsqrtf((float)c) : 0.0f;
    }
}

// ---------------- h = x @ g, packed to bf16 [node][ch][k] ----------------
#define H_NPB 8
__global__ __launch_bounds__(256, 2) void h_kernel(const float* __restrict__ x,
                                                   const float* __restrict__ g) {
    __shared__ float xs[H_NPB][IN_F];
    __shared__ unsigned short hs[H_NPB][OUT_F][KK];
    int t = threadIdx.x;             // column (k = t>>6, ch = t&63)
    int n0 = blockIdx.x * H_NPB;
#pragma unroll
    for (int r = 0; r < 2; ++r) {
        int idx = r * 256 + t;
        int nn = idx >> 6, ii = idx & 63;
        int n = n0 + nn;
        xs[nn][ii] = (n < N_NODES) ? x[n * IN_F + ii] : 0.0f;
    }
    __syncthreads();
    float acc[H_NPB];
#pragma unroll
    for (int n = 0; n < H_NPB; ++n) acc[n] = 0.0f;
#pragma unroll 8
    for (int i = 0; i < IN_F; ++i) {
        float gv = g[i * KOUT + t];
#pragma unroll
        for (int n = 0; n < H_NPB; ++n) acc[n] += xs[n][i] * gv;
    }
    int k = t >> 6, ch = t & 63;
#pragma unroll
    for (int n = 0; n < H_NPB; ++n) hs[n][ch][k] = f2bf(acc[n]);
    __syncthreads();
#pragma unroll
    for (int r = 0; r < 2; ++r) {
        int idx = r * 256 + t;
        int nn = idx >> 6, cc = idx & 63;
        int node = n0 + nn;
        if (node < N_NODES) {
            const unsigned short* p = &hs[nn][cc][0];
            uint2 v;
            v.x = (unsigned int)p[0] | ((unsigned int)p[1] << 16);
            v.y = (unsigned int)p[2] | ((unsigned int)p[3] << 16);
            g_hp[(size_t)node * OUT_F + cc] = v;
        }
    }
}

// ---------------- scatter: gaussian weights -> dst-bucketed CSR ----------------
__global__ __launch_bounds__(256, 4) void scatter_kernel(const int* __restrict__ src,
                                                         const int* __restrict__ dst,
                                                         const float* __restrict__ mu) {
    int e = blockIdx.x * blockDim.x + threadIdx.x;
    if (e >= N_EDGES) return;
    int s = src[e];
    int d = dst[e];
    float a0 = g_isd[s];
    float a1 = g_isd[d];
    float w[KK];
#pragma unroll
    for (int k = 0; k < KK; ++k) {
        float d0 = a0 - mu[k * 2 + 0];
        float d1 = a1 - mu[k * 2 + 1];
        w[k] = __expf(g_w2[k * 2 + 0] * d0 * d0 + g_w2[k * 2 + 1] * d1 * d1);
    }
    int pos = atomicAdd(&g_cur[d], 1);
    g_csrc[pos] = s;
    g_cgauss[pos] = make_float4(w[0], w[1], w[2], w[3]);
}

// ---------------- aggregate (wave per node) + fused mean/root/bias epilogue ----------------
__global__ __launch_bounds__(256, 4) void agg_kernel(const float* __restrict__ x,
                                                     const float* __restrict__ rw,
                                                     const float* __restrict__ bias,
                                                     float* __restrict__ out) {
    __shared__ float xs[4][IN_F];
    int t = threadIdx.x;
    int wid = t >> 6;                // wave in block = node slot
    int lane = t & 63;               // output channel
    int n0 = blockIdx.x * 4;
    int nld = n0 + wid;
    xs[wid][lane] = (nld < N_NODES) ? x[nld * IN_F + lane] : 0.0f;
    __syncthreads();
    int n = n0 + wid;
    if (n >= N_NODES) return;

    int off = g_off[n];
    int end = g_off[n + 1];
    float acc = 0.0f;
    int j = off;
    for (; j + 1 < end; j += 2) {       // 2 gathers in flight
        int s0 = g_csrc[j], s1 = g_csrc[j + 1];
        float4 w0 = g_cgauss[j], w1 = g_cgauss[j + 1];
        uint2 h0 = g_hp[(size_t)s0 * OUT_F + lane];
        uint2 h1 = g_hp[(size_t)s1 * OUT_F + lane];
        acc += bflo(h0.x) * w0.x + bfhi(h0.x) * w0.y + bflo(h0.y) * w0.z + bfhi(h0.y) * w0.w;
        acc += bflo(h1.x) * w1.x + bfhi(h1.x) * w1.y + bflo(h1.y) * w1.z + bfhi(h1.y) * w1.w;
    }
    if (j < end) {
        int s0 = g_csrc[j];
        float4 w0 = g_cgauss[j];
        uint2 h0 = g_hp[(size_t)s0 * OUT_F + lane];
        acc += bflo(h0.x) * w0.x + bfhi(h0.x) * w0.y + bflo(h0.y) * w0.z + bfhi(h0.y) * w0.w;
    }

    float root = bias[lane];
#pragma unroll 8
    for (int i = 0; i < IN_F; ++i) root += xs[wid][i] * rw[i * OUT_F + lane];

    int c = end - off;
    float dv = (c > 0) ? (float)c : 1.0f;
    out[(size_t)n * OUT_F + lane] = acc / dv + root;
}

extern "C" void kernel_launch(void* const* d_in, const int* in_sizes, int n_in,
                              void* d_out, int out_size, void* d_ws, size_t ws_size,
                              hipStream_t stream) {
    const float* x     = (const float*)d_in[0];
    const int*   ei    = (const int*)d_in[1];     // int64 in reference -> int32 from harness
    const float* g     = (const float*)d_in[2];
    const float* mu    = (const float*)d_in[3];
    const float* sigma = (const float*)d_in[4];
    const float* rw    = (const float*)d_in[5];
    const float* bias  = (const float*)d_in[6];
    float* out = (float*)d_out;

    const int* src = ei;            // [2,E] row-major
    const int* dst = ei + N_EDGES;

    zero_kernel<<<NB, 256, 0, stream>>>();
    deg_kernel<<<(N_EDGES + 255) / 256, 256, 0, stream>>>(dst);
    scan1_kernel<<<NB, 256, 0, stream>>>();
    scan2_kernel<<<1, 512, 0, stream>>>();
    scan3_kernel<<<NB, 256, 0, stream>>>(sigma);
    h_kernel<<<(N_NODES + H_NPB - 1) / H_NPB, 256, 0, stream>>>(x, g);
    scatter_kernel<<<(N_EDGES + 255) / 256, 256, 0, stream>>>(src, dst, mu);
    agg_kernel<<<(N_NODES + 3) / 4, 256, 0, stream>>>(x, rw, bias, out);
}

// Round 7
// 387.406 us; speedup vs baseline: 8.9838x; 1.2860x over previous
//
#include <hip/hip_runtime.h>
#include <math.h>

#define N_NODES 100000
#define N_EDGES 1600000
#define IN_F 64
#define OUT_F 64
#define KK 4
#define KY 320               // 256 (k*64+i) + 64 (x concat for root_w)
#define EPS 1e-15f
#define NB ((N_NODES + 255) / 256)   // 391 scan blocks

typedef __attribute__((ext_vector_type(8))) short short8;    // 8 x bf16 (4 VGPRs)
typedef __attribute__((ext_vector_type(4))) float float4v;   // MFMA acc

// ---- module-global scratch ----
__device__ int            g_cnt[N_NODES];
__device__ int            g_off[N_NODES + 1];
__device__ int            g_cur[N_NODES];
__device__ int            g_bsum[512];
__device__ float          g_isd[N_NODES];
__device__ float          g_w2[KK * 2];                      // -0.5/(eps+sigma^2)
__device__ unsigned short g_xp[(size_t)N_NODES * IN_F];      // bf16 x, 12.8 MB (gather operand)
__device__ uint4          g_centry[N_EDGES];                 // {src, w01, w23, 0} dst-bucket order, 25.6 MB
__device__ unsigned short g_Y[(size_t)N_NODES * KY];         // bf16 [node][kk], 64 MB
__device__ unsigned short g_gt[OUT_F * KY];                  // G'^T [o][kk] bf16, 40 KB

static __device__ __forceinline__ unsigned short f2bf(float f) {
    unsigned int u = __float_as_uint(f);
    unsigned int r = u + 0x7fffu + ((u >> 16) & 1u);   // RNE
    return (unsigned short)(r >> 16);
}
static __device__ __forceinline__ float bflo(unsigned int u) { return __uint_as_float(u << 16); }
static __device__ __forceinline__ float bfhi(unsigned int u) { return __uint_as_float(u & 0xffff0000u); }
static __device__ __forceinline__ float bfs(unsigned short u) { return __uint_as_float((unsigned int)u << 16); }

// ---------------- zero counts ----------------
__global__ void zero_kernel() {
    int i = blockIdx.x * blockDim.x + threadIdx.x;
    if (i < N_NODES) g_cnt[i] = 0;
    if (i == 0) g_off[N_NODES] = N_EDGES;
}

// ---------------- in-degree histogram (int) ----------------
__global__ void deg_kernel(const int* __restrict__ dst) {
    int e = blockIdx.x * blockDim.x + threadIdx.x;
    if (e < N_EDGES) atomicAdd(&g_cnt[dst[e]], 1);
}

// ---------------- scan 1: per-block exclusive scan of g_cnt ----------------
__global__ void scan1_kernel() {
    __shared__ int sh[256];
    int t = threadIdx.x;
    int i = blockIdx.x * 256 + t;
    int c = (i < N_NODES) ? g_cnt[i] : 0;
    sh[t] = c;
    __syncthreads();
#pragma unroll
    for (int d = 1; d < 256; d <<= 1) {
        int v = (t >= d) ? sh[t - d] : 0;
        __syncthreads();
        sh[t] += v;
        __syncthreads();
    }
    int incl = sh[t];
    if (i < N_NODES) g_off[i] = incl - c;
    if (t == 255) g_bsum[blockIdx.x] = incl;
}

// ---------------- scan 2: exclusive scan of block sums ----------------
__global__ void scan2_kernel() {
    __shared__ int sh[512];
    int t = threadIdx.x;
    int v = (t < NB) ? g_bsum[t] : 0;
    sh[t] = v;
    __syncthreads();
#pragma unroll
    for (int d = 1; d < 512; d <<= 1) {
        int u = (t >= d) ? sh[t - d] : 0;
        __syncthreads();
        sh[t] += u;
        __syncthreads();
    }
    if (t < NB) g_bsum[t] = sh[t] - v;
}

// ---------------- scan 3: add-back + cursors + isd + w2 ----------------
__global__ void scan3_kernel(const float* __restrict__ sigma) {
    int i = blockIdx.x * blockDim.x + threadIdx.x;
    if (i < KK * 2) {
        float s = sigma[i];
        g_w2[i] = -0.5f / (EPS + s * s);
    }
    if (i < N_NODES) {
        int off = g_off[i] + g_bsum[i >> 8];
        g_off[i] = off;
        g_cur[i] = off;
        int c = g_cnt[i];
        g_isd[i] = (c > 0) ? rsqrtf((float)c) : 0.0f;
    }
}

// ---------------- xpack: x -> bf16 (gather operand) ----------------
__global__ void xpack_kernel(const float* __restrict__ x) {
    int t = blockIdx.x * blockDim.x + threadIdx.x;   // over N*32 uint pairs
    if (t < N_NODES * (IN_F / 2)) {
        float a = x[2 * t], b = x[2 * t + 1];
        ((unsigned int*)g_xp)[t] = (unsigned int)f2bf(a) | ((unsigned int)f2bf(b) << 16);
    }
}

// ---------------- pack_g: G'^T[o][kk] bf16 (kk = k*64+i for kk<256, else root_w row kk-256) ----------------
__global__ void packg_kernel(const float* __restrict__ g, const float* __restrict__ rw) {
    int t = blockIdx.x * blockDim.x + threadIdx.x;   // over 64*320
    if (t < OUT_F * KY) {
        int o = t / KY, kk = t % KY;
        float v;
        if (kk < 256) {
            int k = kk >> 6, i = kk & 63;
            v = g[i * 256 + k * 64 + o];
        } else {
            v = rw[(kk - 256) * 64 + o];
        }
        g_gt[o * KY + kk] = f2bf(v);
    }
}

// ---------------- scatter: gaussian weights + src -> dst-bucketed CSR (one 16B line/edge) ----------------
__global__ __launch_bounds__(256, 4) void scatter_kernel(const int* __restrict__ src,
                                                         const int* __restrict__ dst,
                                                         const float* __restrict__ mu) {
    int e = blockIdx.x * blockDim.x + threadIdx.x;
    if (e >= N_EDGES) return;
    int s = src[e];
    int d = dst[e];
    float a0 = g_isd[s];
    float a1 = g_isd[d];
    float w[KK];
#pragma unroll
    for (int k = 0; k < KK; ++k) {
        float d0 = a0 - mu[k * 2 + 0];
        float d1 = a1 - mu[k * 2 + 1];
        w[k] = __expf(g_w2[k * 2 + 0] * d0 * d0 + g_w2[k * 2 + 1] * d1 * d1);
    }
    unsigned int w01 = (unsigned int)f2bf(w[0]) | ((unsigned int)f2bf(w[1]) << 16);
    unsigned int w23 = (unsigned int)f2bf(w[2]) | ((unsigned int)f2bf(w[3]) << 16);
    int pos = atomicAdd(&g_cur[d], 1);
    g_centry[pos] = make_uint4((unsigned int)s, w01, w23, 0u);
}

// ---------------- aggregate: wave per node; gather bf16 x rows (128B/edge); y in regs ----------------
__global__ __launch_bounds__(256, 8) void agg_kernel() {
    int t = threadIdx.x;
    int wid = t >> 6, lane = t & 63;
    int n = blockIdx.x * 4 + wid;
    if (n >= N_NODES) return;
    int off = g_off[n], end = g_off[n + 1];
    float y0 = 0.f, y1 = 0.f, y2 = 0.f, y3 = 0.f;
    int j = off;
    for (; j + 1 < end; j += 2) {
        uint4 c0 = g_centry[j];
        uint4 c1 = g_centry[j + 1];
        float xv0 = bfs(g_xp[(size_t)c0.x * IN_F + lane]);
        float xv1 = bfs(g_xp[(size_t)c1.x * IN_F + lane]);
        y0 += bflo(c0.y) * xv0; y1 += bfhi(c0.y) * xv0;
        y2 += bflo(c0.z) * xv0; y3 += bfhi(c0.z) * xv0;
        y0 += bflo(c1.y) * xv1; y1 += bfhi(c1.y) * xv1;
        y2 += bflo(c1.z) * xv1; y3 += bfhi(c1.z) * xv1;
    }
    if (j < end) {
        uint4 c0 = g_centry[j];
        float xv0 = bfs(g_xp[(size_t)c0.x * IN_F + lane]);
        y0 += bflo(c0.y) * xv0; y1 += bfhi(c0.y) * xv0;
        y2 += bflo(c0.z) * xv0; y3 += bfhi(c0.z) * xv0;
    }
    int c = end - off;
    float inv = 1.0f / ((c > 0) ? (float)c : 1.0f);
    size_t base = (size_t)n * KY;
    g_Y[base +   0 + lane] = f2bf(y0 * inv);
    g_Y[base +  64 + lane] = f2bf(y1 * inv);
    g_Y[base + 128 + lane] = f2bf(y2 * inv);
    g_Y[base + 192 + lane] = f2bf(y3 * inv);
    g_Y[base + 256 + lane] = g_xp[(size_t)n * IN_F + lane];   // x concat for root_w
}

// ---------------- MFMA epilogue: out = Y @ G' + bias ([100k,320]@[320,64] bf16) ----------------
// block = 4 waves = one 16-node tile; wave w owns o-cols w*16..w*16+15.
// A[m=lane&15][k=quad*8+j] (m120-verified); B mirrors with n=lane&15; D col=lane&15,row=quad*4+reg (m89).
__global__ __launch_bounds__(256, 3) void out_kernel(const float* __restrict__ bias,
                                                     float* __restrict__ out) {
    __shared__ unsigned short yt[16][328];   // 320 + 8 pad (row stride 656B: 16B-aligned, conflict-optimal)
    __shared__ unsigned short gt[64][328];
    int t = threadIdx.x;
    int n0 = blockIdx.x * 16;
    // stage G'^T: 64 rows x 40 uint4
    for (int f = t; f < 64 * 40; f += 256) {
        int r = f / 40, c = f % 40;
        *(uint4*)&gt[r][c * 8] = ((const uint4*)g_gt)[f];
    }
    // stage Y tile: 16 rows x 40 uint4, coalesced
    for (int f = t; f < 16 * 40; f += 256) {
        int r = f / 40, c = f % 40;
        *(uint4*)&yt[r][c * 8] = ((const uint4*)(g_Y + (size_t)(n0 + r) * KY))[c];
    }
    __syncthreads();
    int wv = t >> 6, L = t & 63;
    int m = L & 15, q = L >> 4;
    int ow = wv * 16;
    float4v acc = {0.f, 0.f, 0.f, 0.f};
#pragma unroll
    for (int s = 0; s < 10; ++s) {
        short8 a = *(const short8*)&yt[m][s * 32 + q * 8];
        short8 b = *(const short8*)&gt[ow + m][s * 32 + q * 8];
        acc = __builtin_amdgcn_mfma_f32_16x16x32_bf16(a, b, acc, 0, 0, 0);
    }
    int o = ow + m;
    float bv = bias[o];
#pragma unroll
    for (int r = 0; r < 4; ++r) {
        int node = n0 + q * 4 + r;
        out[(size_t)node * OUT_F + o] = acc[r] + bv;
    }
}

extern "C" void kernel_launch(void* const* d_in, const int* in_sizes, int n_in,
                              void* d_out, int out_size, void* d_ws, size_t ws_size,
                              hipStream_t stream) {
    const float* x     = (const float*)d_in[0];
    const int*   ei    = (const int*)d_in[1];     // int64 in reference -> int32 from harness
    const float* g     = (const float*)d_in[2];
    const float* mu    = (const float*)d_in[3];
    const float* sigma = (const float*)d_in[4];
    const float* rw    = (const float*)d_in[5];
    const float* bias  = (const float*)d_in[6];
    float* out = (float*)d_out;

    const int* src = ei;            // [2,E] row-major
    const int* dst = ei + N_EDGES;

    zero_kernel<<<NB, 256, 0, stream>>>();
    deg_kernel<<<(N_EDGES + 255) / 256, 256, 0, stream>>>(dst);
    scan1_kernel<<<NB, 256, 0, stream>>>();
    scan2_kernel<<<1, 512, 0, stream>>>();
    scan3_kernel<<<NB, 256, 0, stream>>>(sigma);
    xpack_kernel<<<(N_NODES * 32 + 255) / 256, 256, 0, stream>>>(x);
    packg_kernel<<<(OUT_F * KY + 255) / 256, 256, 0, stream>>>(g, rw);
    scatter_kernel<<<(N_EDGES + 255) / 256, 256, 0, stream>>>(src, dst, mu);
    agg_kernel<<<(N_NODES + 3) / 4, 256, 0, stream>>>();
    out_kernel<<<N_NODES / 16, 256, 0, stream>>>(bias, out);
}

// Round 8
// 321.689 us; speedup vs baseline: 10.8191x; 1.2043x over previous
//
#include <hip/hip_runtime.h>
#include <math.h>

#define N_NODES 100000
#define N_EDGES 1600000
#define IN_F 64
#define OUT_F 64
#define KK 4
#define KY 320               // 256 (k*64+i) + 64 (x concat for root_w)
#define EPS 1e-15f
#define NB ((N_NODES + 255) / 256)   // 391 scan blocks

typedef __attribute__((ext_vector_type(8))) short short8;    // 8 x bf16 (4 VGPRs)
typedef __attribute__((ext_vector_type(4))) float float4v;   // MFMA acc

// ---- module-global scratch ----
__device__ int            g_cnt[N_NODES];
__device__ int            g_off[N_NODES + 1];
__device__ int            g_cur[N_NODES];
__device__ int            g_bsum[512];
__device__ float          g_isd[N_NODES];
__device__ float          g_w2[KK * 2];                      // -0.5/(eps+sigma^2)
__device__ unsigned short g_xp[(size_t)N_NODES * IN_F];      // bf16 x, 12.8 MB (gather operand)
__device__ uint4          g_centry[N_EDGES];                 // {src, w01, w23, 0} dst-bucket order, 25.6 MB
__device__ unsigned short g_gt[OUT_F * KY];                  // G'^T [o][kk] bf16, 40 KB

static __device__ __forceinline__ unsigned short f2bf(float f) {
    unsigned int u = __float_as_uint(f);
    unsigned int r = u + 0x7fffu + ((u >> 16) & 1u);   // RNE
    return (unsigned short)(r >> 16);
}
static __device__ __forceinline__ float bflo(unsigned int u) { return __uint_as_float(u << 16); }
static __device__ __forceinline__ float bfhi(unsigned int u) { return __uint_as_float(u & 0xffff0000u); }
static __device__ __forceinline__ unsigned int pk(float a, float b) {
    return (unsigned int)f2bf(a) | ((unsigned int)f2bf(b) << 16);
}

// ---------------- zero counts ----------------
__global__ void zero_kernel() {
    int i = blockIdx.x * blockDim.x + threadIdx.x;
    if (i < N_NODES) g_cnt[i] = 0;
    if (i == 0) g_off[N_NODES] = N_EDGES;
}

// ---------------- in-degree histogram (int) ----------------
__global__ void deg_kernel(const int* __restrict__ dst) {
    int e = blockIdx.x * blockDim.x + threadIdx.x;
    if (e < N_EDGES) atomicAdd(&g_cnt[dst[e]], 1);
}

// ---------------- scan 1: per-block exclusive scan of g_cnt ----------------
__global__ void scan1_kernel() {
    __shared__ int sh[256];
    int t = threadIdx.x;
    int i = blockIdx.x * 256 + t;
    int c = (i < N_NODES) ? g_cnt[i] : 0;
    sh[t] = c;
    __syncthreads();
#pragma unroll
    for (int d = 1; d < 256; d <<= 1) {
        int v = (t >= d) ? sh[t - d] : 0;
        __syncthreads();
        sh[t] += v;
        __syncthreads();
    }
    int incl = sh[t];
    if (i < N_NODES) g_off[i] = incl - c;
    if (t == 255) g_bsum[blockIdx.x] = incl;
}

// ---------------- scan 2: exclusive scan of block sums ----------------
__global__ void scan2_kernel() {
    __shared__ int sh[512];
    int t = threadIdx.x;
    int v = (t < NB) ? g_bsum[t] : 0;
    sh[t] = v;
    __syncthreads();
#pragma unroll
    for (int d = 1; d < 512; d <<= 1) {
        int u = (t >= d) ? sh[t - d] : 0;
        __syncthreads();
        sh[t] += u;
        __syncthreads();
    }
    if (t < NB) g_bsum[t] = sh[t] - v;
}

// ---------------- scan 3: add-back + cursors + isd + w2 ----------------
__global__ void scan3_kernel(const float* __restrict__ sigma) {
    int i = blockIdx.x * blockDim.x + threadIdx.x;
    if (i < KK * 2) {
        float s = sigma[i];
        g_w2[i] = -0.5f / (EPS + s * s);
    }
    if (i < N_NODES) {
        int off = g_off[i] + g_bsum[i >> 8];
        g_off[i] = off;
        g_cur[i] = off;
        int c = g_cnt[i];
        g_isd[i] = (c > 0) ? rsqrtf((float)c) : 0.0f;
    }
}

// ---------------- xpack: x -> bf16 (gather operand) ----------------
__global__ void xpack_kernel(const float* __restrict__ x) {
    int t = blockIdx.x * blockDim.x + threadIdx.x;   // over N*32 uint pairs
    if (t < N_NODES * (IN_F / 2)) {
        float a = x[2 * t], b = x[2 * t + 1];
        ((unsigned int*)g_xp)[t] = pk(a, b);
    }
}

// ---------------- pack_g: G'^T[o][kk] bf16 (kk = k*64+i for kk<256, else root_w row kk-256) ----------------
__global__ void packg_kernel(const float* __restrict__ g, const float* __restrict__ rw) {
    int t = blockIdx.x * blockDim.x + threadIdx.x;   // over 64*320
    if (t < OUT_F * KY) {
        int o = t / KY, kk = t % KY;
        float v;
        if (kk < 256) {
            int k = kk >> 6, i = kk & 63;
            v = g[i * 256 + k * 64 + o];
        } else {
            v = rw[(kk - 256) * 64 + o];
        }
        g_gt[o * KY + kk] = f2bf(v);
    }
}

// ---------------- scatter: gaussian weights + src -> dst-bucketed CSR (one 16B line/edge) ----------------
__global__ __launch_bounds__(256, 4) void scatter_kernel(const int* __restrict__ src,
                                                         const int* __restrict__ dst,
                                                         const float* __restrict__ mu) {
    int e = blockIdx.x * blockDim.x + threadIdx.x;
    if (e >= N_EDGES) return;
    int s = src[e];
    int d = dst[e];
    float a0 = g_isd[s];
    float a1 = g_isd[d];
    float w[KK];
#pragma unroll
    for (int k = 0; k < KK; ++k) {
        float d0 = a0 - mu[k * 2 + 0];
        float d1 = a1 - mu[k * 2 + 1];
        w[k] = __expf(g_w2[k * 2 + 0] * d0 * d0 + g_w2[k * 2 + 1] * d1 * d1);
    }
    int pos = atomicAdd(&g_cur[d], 1);
    g_centry[pos] = make_uint4((unsigned int)s, pk(w[0], w[1]), pk(w[2], w[3]), 0u);
}

// ---------------- fused aggregate + MFMA epilogue ----------------
// Block = 4 waves = 32 nodes (100000/32 = 3125 blocks exactly).
// Phase 1: 8-lane group per node; lane c owns channels c*8..c*8+7 (16 B/lane gathers,
//          one wave-instruction fetches 8 edges = 1 KB). 32 fp32 accs/lane, no reduction.
// Phase 2: y (bf16) -> LDS [32][328]; wave wv computes o-cols wv*16..+15 for both
//          16-node tiles via mfma_f32_16x16x32_bf16 (A layout m120, C/D layout m89 --
//          identical fragment scheme as the R7-verified out_kernel).
__global__ __launch_bounds__(256, 4) void fused_kernel(const float* __restrict__ bias,
                                                       float* __restrict__ out) {
    __shared__ unsigned short yt[32][328];   // 656 B row stride: 16B-aligned, odd*16 -> low conflict
    int t = threadIdx.x;
    int wv = t >> 6, L = t & 63;
    int grp = L >> 3, c = L & 7;
    int n0 = blockIdx.x * 32;
    int n = n0 + wv * 8 + grp;               // always < N_NODES

    int off = g_off[n], end = g_off[n + 1];
    float y[KK][8];
#pragma unroll
    for (int k = 0; k < KK; ++k)
#pragma unroll
        for (int i = 0; i < 8; ++i) y[k][i] = 0.0f;

    int j = off;
    for (; j + 1 < end; j += 2) {            // 2 gathers in flight
        uint4 c0 = g_centry[j];
        uint4 c1 = g_centry[j + 1];
        uint4 xv0 = *(const uint4*)(g_xp + (size_t)c0.x * IN_F + c * 8);
        uint4 xv1 = *(const uint4*)(g_xp + (size_t)c1.x * IN_F + c * 8);
        float w0[KK] = {bflo(c0.y), bfhi(c0.y), bflo(c0.z), bfhi(c0.z)};
        float w1[KK] = {bflo(c1.y), bfhi(c1.y), bflo(c1.z), bfhi(c1.z)};
        float f0[8] = {bflo(xv0.x), bfhi(xv0.x), bflo(xv0.y), bfhi(xv0.y),
                       bflo(xv0.z), bfhi(xv0.z), bflo(xv0.w), bfhi(xv0.w)};
        float f1[8] = {bflo(xv1.x), bfhi(xv1.x), bflo(xv1.y), bfhi(xv1.y),
                       bflo(xv1.z), bfhi(xv1.z), bflo(xv1.w), bfhi(xv1.w)};
#pragma unroll
        for (int k = 0; k < KK; ++k)
#pragma unroll
            for (int i = 0; i < 8; ++i) y[k][i] += w0[k] * f0[i] + w1[k] * f1[i];
    }
    if (j < end) {
        uint4 c0 = g_centry[j];
        uint4 xv0 = *(const uint4*)(g_xp + (size_t)c0.x * IN_F + c * 8);
        float w0[KK] = {bflo(c0.y), bfhi(c0.y), bflo(c0.z), bfhi(c0.z)};
        float f0[8] = {bflo(xv0.x), bfhi(xv0.x), bflo(xv0.y), bfhi(xv0.y),
                       bflo(xv0.z), bfhi(xv0.z), bflo(xv0.w), bfhi(xv0.w)};
#pragma unroll
        for (int k = 0; k < KK; ++k)
#pragma unroll
            for (int i = 0; i < 8; ++i) y[k][i] += w0[k] * f0[i];
    }

    int cdeg = end - off;
    float inv = 1.0f / ((cdeg > 0) ? (float)cdeg : 1.0f);
    int row = wv * 8 + grp;
#pragma unroll
    for (int k = 0; k < KK; ++k) {
        uint4 v;
        v.x = pk(y[k][0] * inv, y[k][1] * inv);
        v.y = pk(y[k][2] * inv, y[k][3] * inv);
        v.z = pk(y[k][4] * inv, y[k][5] * inv);
        v.w = pk(y[k][6] * inv, y[k][7] * inv);
        *(uint4*)&yt[row][k * 64 + c * 8] = v;
    }
    *(uint4*)&yt[row][256 + c * 8] = *(const uint4*)(g_xp + (size_t)n * IN_F + c * 8);
    __syncthreads();

    // ---- MFMA phase ----
    int m = L & 15, q = L >> 4;
    int o = wv * 16 + m;
    float bv = bias[o];
#pragma unroll
    for (int T = 0; T < 2; ++T) {
        float4v acc = {0.f, 0.f, 0.f, 0.f};
#pragma unroll
        for (int s = 0; s < 10; ++s) {
            short8 a = *(const short8*)&yt[T * 16 + m][s * 32 + q * 8];
            short8 b = *(const short8*)&g_gt[(size_t)o * KY + s * 32 + q * 8];
            acc = __builtin_amdgcn_mfma_f32_16x16x32_bf16(a, b, acc, 0, 0, 0);
        }
#pragma unroll
        for (int r = 0; r < 4; ++r) {
            int node = n0 + T * 16 + q * 4 + r;
            out[(size_t)node * OUT_F + o] = acc[r] + bv;
        }
    }
}

extern "C" void kernel_launch(void* const* d_in, const int* in_sizes, int n_in,
                              void* d_out, int out_size, void* d_ws, size_t ws_size,
                              hipStream_t stream) {
    const float* x     = (const float*)d_in[0];
    const int*   ei    = (const int*)d_in[1];     // int64 in reference -> int32 from harness
    const float* g     = (const float*)d_in[2];
    const float* mu    = (const float*)d_in[3];
    const float* sigma = (const float*)d_in[4];
    const float* rw    = (const float*)d_in[5];
    const float* bias  = (const float*)d_in[6];
    float* out = (float*)d_out;

    const int* src = ei;            // [2,E] row-major
    const int* dst = ei + N_EDGES;

    zero_kernel<<<NB, 256, 0, stream>>>();
    deg_kernel<<<(N_EDGES + 255) / 256, 256, 0, stream>>>(dst);
    scan1_kernel<<<NB, 256, 0, stream>>>();
    scan2_kernel<<<1, 512, 0, stream>>>();
    scan3_kernel<<<NB, 256, 0, stream>>>(sigma);
    xpack_kernel<<<(N_NODES * 32 + 255) / 256, 256, 0, stream>>>(x);
    packg_kernel<<<(OUT_F * KY + 255) / 256, 256, 0, stream>>>(g, rw);
    scatter_kernel<<<(N_EDGES + 255) / 256, 256, 0, stream>>>(src, dst, mu);
    fused_kernel<<<N_NODES / 32, 256, 0, stream>>>(bias, out);
}